// Round 9
// baseline (346.000 us; speedup 1.0000x reference)
//
#include <hip/hip_runtime.h>

#define S_LEN 2048
#define NHQ 32
#define NKV 8
#define HD 64
#define DMODEL 2048   // NHQ*HD
#define DKV 512       // NKV*HD

typedef unsigned short ushort_t;
typedef unsigned int uint_t;

typedef __attribute__((ext_vector_type(8))) short bf16x8;
typedef __attribute__((ext_vector_type(4))) float f32x4;

__device__ __forceinline__ float b2f(ushort_t h) {
  union { uint_t u; float f; } v;
  v.u = ((uint_t)h) << 16;
  return v.f;
}
// round-to-nearest-even fp32 -> bf16
__device__ __forceinline__ ushort_t f2b(float f) {
  union { float f; uint_t u; } v;
  v.f = f;
  uint_t r = v.u + 0x7fffu + ((v.u >> 16) & 1u);
  return (ushort_t)(r >> 16);
}
__device__ __forceinline__ uint_t pack2(float lo, float hi) {
  return (uint_t)f2b(lo) | ((uint_t)f2b(hi) << 16);
}

union BF8 { uint4 v; ushort_t s[8]; };

// x fp32 -> bf16 flat (8 elems/thread)
__global__ void xb_kernel(const float* __restrict__ X, ushort_t* __restrict__ XB) {
  int i = (blockIdx.x * 256 + threadIdx.x) * 8;
  float4 a = *(const float4*)(X + i);
  float4 b = *(const float4*)(X + i + 4);
  BF8 u;
  u.s[0] = f2b(a.x); u.s[1] = f2b(a.y); u.s[2] = f2b(a.z); u.s[3] = f2b(a.w);
  u.s[4] = f2b(b.x); u.s[5] = f2b(b.y); u.s[6] = f2b(b.z); u.s[7] = f2b(b.w);
  *(uint4*)(XB + i) = u.v;
}

// W [K=2048][N] fp32 -> WT [N][K] bf16 (64x64 LDS tiles)
__global__ __launch_bounds__(256) void wT_kernel(const float* __restrict__ W,
                                                 ushort_t* __restrict__ WT,
                                                 int K, int N) {
  __shared__ ushort_t T[64][66];
  const int tid = threadIdx.x;
  const int r0 = blockIdx.x * 64;   // K dim
  const int c0 = blockIdx.y * 64;   // N dim
  {
    const int rl = tid >> 2, cp = (tid & 3) * 16;
    const float* p = W + (size_t)(r0 + rl) * N + c0 + cp;
    float v[16];
    *(float4*)(v)      = *(const float4*)(p);
    *(float4*)(v + 4)  = *(const float4*)(p + 4);
    *(float4*)(v + 8)  = *(const float4*)(p + 8);
    *(float4*)(v + 12) = *(const float4*)(p + 12);
    #pragma unroll
    for (int j = 0; j < 16; ++j) T[cp + j][rl] = f2b(v[j]);
  }
  __syncthreads();
  {
    const int cl = tid >> 2, rp = (tid & 3) * 16;
    uint_t u[8];
    #pragma unroll
    for (int i = 0; i < 8; ++i) u[i] = *(const uint_t*)&T[cl][rp + 2 * i];
    ushort_t* outp = WT + (size_t)(c0 + cl) * K + r0 + rp;
    *(uint4*)(outp)     = make_uint4(u[0], u[1], u[2], u[3]);
    *(uint4*)(outp + 8) = make_uint4(u[4], u[5], u[6], u[7]);
  }
}

// GEMM core, 128(M)x64(N) tile, BK=32, 4 waves each 64x32 (4x2 MFMA tiles).
// A bf16 [M][K], BT bf16 [N][K] row-major.
__device__ __forceinline__ void gemm_core64(const ushort_t* __restrict__ A,
                                            const ushort_t* __restrict__ BT,
                                            int K, int tile_m, int tile_n,
                                            f32x4 (&acc)[4][2],
                                            ushort_t (*As)[40], ushort_t (*Bs)[40]) {
  const int tid = threadIdx.x;
  const int lane = tid & 63;
  const int w = tid >> 6;
  const int wr = (w >> 1) * 64, wc = (w & 1) * 32;
  const int lm = lane & 15, kq = lane >> 4;
  const int sra = tid >> 1, ska = (tid & 1) * 16;
  const int srb = tid >> 2, skb = (tid & 3) * 8;

  #pragma unroll
  for (int i = 0; i < 4; ++i)
    #pragma unroll
    for (int j = 0; j < 2; ++j) acc[i][j] = {0.f, 0.f, 0.f, 0.f};

  const ushort_t* ap = A  + (size_t)(tile_m + sra) * K + ska;
  const ushort_t* bp = BT + (size_t)(tile_n + srb) * K + skb;

  for (int kt = 0; kt < K; kt += 32) {
    __syncthreads();
    uint4 a0 = ((const uint4*)(ap + kt))[0], a1 = ((const uint4*)(ap + kt))[1];
    uint4 b0 = *(const uint4*)(bp + kt);
    *(uint4*)&As[sra][ska]     = a0;
    *(uint4*)&As[sra][ska + 8] = a1;
    *(uint4*)&Bs[srb][skb]     = b0;
    __syncthreads();
    bf16x8 af[4], bfr[2];
    #pragma unroll
    for (int i = 0; i < 4; ++i) af[i]  = *(const bf16x8*)&As[wr + 16 * i + lm][kq * 8];
    #pragma unroll
    for (int j = 0; j < 2; ++j) bfr[j] = *(const bf16x8*)&Bs[wc + 16 * j + lm][kq * 8];
    #pragma unroll
    for (int i = 0; i < 4; ++i)
      #pragma unroll
      for (int j = 0; j < 2; ++j)
        acc[i][j] = __builtin_amdgcn_mfma_f32_16x16x32_bf16(af[i], bfr[j], acc[i][j], 0, 0, 0);
  }
}

// Fused q/k/v projection: BT = [wqT|wkT|wvT] (N=3072). Split epilogue.
__global__ __launch_bounds__(256) void gemm_proj(const ushort_t* __restrict__ A,
                                                 const ushort_t* __restrict__ BT,
                                                 ushort_t* __restrict__ Qo,
                                                 float* __restrict__ Ko,
                                                 float* __restrict__ Vo) {
  __shared__ ushort_t As[128][40];
  __shared__ ushort_t Bs[64][40];
  const int lane = threadIdx.x & 63;
  const int w = threadIdx.x >> 6;
  const int wr = (w >> 1) * 64, wc = (w & 1) * 32;
  const int lm = lane & 15, kq = lane >> 4;
  const int tile_m = blockIdx.y * 128, tile_n = blockIdx.x * 64;
  f32x4 acc[4][2];
  gemm_core64(A, BT, DMODEL, tile_m, tile_n, acc, As, Bs);
  #pragma unroll
  for (int i = 0; i < 4; ++i)
    #pragma unroll
    for (int j = 0; j < 2; ++j)
      #pragma unroll
      for (int r = 0; r < 4; ++r) {
        const int row = tile_m + wr + 16 * i + kq * 4 + r;
        const int col = tile_n + wc + 16 * j + lm;
        const float v = acc[i][j][r];
        if (col < 2048)      Qo[(size_t)row * DMODEL + col] = f2b(v);
        else if (col < 2560) Ko[(size_t)row * DKV + col - 2048] = v;
        else                 Vo[(size_t)row * DKV + col - 2560] = v;
      }
}

// Final projection: C fp32 [M][2048]
__global__ __launch_bounds__(256) void gemm_out(const ushort_t* __restrict__ A,
                                                const ushort_t* __restrict__ BT,
                                                float* __restrict__ C) {
  __shared__ ushort_t As[128][40];
  __shared__ ushort_t Bs[64][40];
  const int lane = threadIdx.x & 63;
  const int w = threadIdx.x >> 6;
  const int wr = (w >> 1) * 64, wc = (w & 1) * 32;
  const int lm = lane & 15, kq = lane >> 4;
  const int tile_m = blockIdx.y * 128, tile_n = blockIdx.x * 64;
  f32x4 acc[4][2];
  gemm_core64(A, BT, DMODEL, tile_m, tile_n, acc, As, Bs);
  #pragma unroll
  for (int i = 0; i < 4; ++i)
    #pragma unroll
    for (int j = 0; j < 2; ++j)
      #pragma unroll
      for (int r = 0; r < 4; ++r) {
        const int row = tile_m + wr + 16 * i + kq * 4 + r;
        const int col = tile_n + wc + 16 * j + lm;
        C[(size_t)row * DMODEL + col] = acc[i][j][r];
      }
}

// Fused rope(K) in-place fp32 + bf16 KB [hk][s][64] copy.
__global__ void rope_kb_kernel(float* Kio, ushort_t* __restrict__ KB,
                               const float* __restrict__ cosT, const float* __restrict__ sinT) {
  int idx = blockIdx.x * 256 + threadIdx.x;   // < S*8*32
  int d = idx & 31;
  int hk = (idx >> 5) & 7;
  int s = idx >> 8;
  float* p = Kio + (size_t)s * DKV + hk * HD + d;
  float x1 = p[0], x2 = p[32];
  float c = cosT[s * 64 + d], sn = sinT[s * 64 + d];
  float n1 = x1 * c - x2 * sn;
  float n2 = x1 * sn + x2 * c;
  p[0] = n1; p[32] = n2;
  ushort_t* kb = KB + (size_t)hk * S_LEN * HD + (size_t)s * HD + d;
  kb[0] = f2b(n1); kb[32] = f2b(n2);
}

// V: fp32 [s][512] -> bf16 transposed VT [hk][64][s]
__global__ __launch_bounds__(256) void vt_kernel(const float* __restrict__ V,
                                                 ushort_t* __restrict__ VT) {
  __shared__ ushort_t T[64][66];
  const int tid = threadIdx.x;
  const int s0 = blockIdx.x * 64;
  const int hk = blockIdx.y;
  {
    const int s_l = tid >> 2, dp = (tid & 3) * 16;
    const float* p = V + (size_t)(s0 + s_l) * DKV + hk * HD + dp;
    float v[16];
    *(float4*)(v)      = *(const float4*)(p);
    *(float4*)(v + 4)  = *(const float4*)(p + 4);
    *(float4*)(v + 8)  = *(const float4*)(p + 8);
    *(float4*)(v + 12) = *(const float4*)(p + 12);
    #pragma unroll
    for (int j = 0; j < 16; ++j) T[dp + j][s_l] = f2b(v[j]);
  }
  __syncthreads();
  {
    const int d_l = tid >> 2, sp = (tid & 3) * 16;
    uint_t u[8];
    #pragma unroll
    for (int i = 0; i < 8; ++i) u[i] = *(const uint_t*)&T[d_l][sp + 2 * i];
    ushort_t* outp = VT + (size_t)hk * HD * S_LEN + (size_t)d_l * S_LEN + s0 + sp;
    *(uint4*)(outp)     = make_uint4(u[0], u[1], u[2], u[3]);
    *(uint4*)(outp + 8) = make_uint4(u[4], u[5], u[6], u[7]);
  }
}

// MFMA flash attention v3: 16-query groups, 2 independent waves per block
// handling paired groups (g, 127-g) -> uniform 33 key-tiles/block; 4096
// waves total (16/CU). Log2-domain online softmax (exp2 = native v_exp).
// RoPE on Q fused at fragment load. Structure = verified attn_mfma2.
__global__ __launch_bounds__(128) void attn_mfma3(const ushort_t* Q,
                                                  const ushort_t* __restrict__ KB,
                                                  const ushort_t* __restrict__ VT,
                                                  const float* __restrict__ cosT,
                                                  const float* __restrict__ sinT,
                                                  ushort_t* O) {
  __shared__ ushort_t Ps[2][16][66];
  const int wv = threadIdx.x >> 6;
  const int lane = threadIdx.x & 63;
  const int lm = lane & 15, kq = lane >> 4;
  const int h = blockIdx.x >> 6;
  const int pr_ = blockIdx.x & 63;
  const int g = wv ? (127 - pr_) : pr_;
  const int q0 = g * 16;
  const int hk = h >> 2;
  const ushort_t* KBh = KB + (size_t)hk * S_LEN * HD;
  const ushort_t* VTh = VT + (size_t)hk * HD * S_LEN;

  // Q B-frag with fused RoPE: q = q0+lm, d = 8kq (+32 for the pair)
  bf16x8 bq[2];
  {
    const int row = q0 + lm;
    const ushort_t* qp = Q + (size_t)row * DMODEL + h * HD + 8 * kq;
    bf16x8 x1v = *(const bf16x8*)qp;
    bf16x8 x2v = *(const bf16x8*)(qp + 32);
    const float* cp = cosT + row * 64 + 8 * kq;
    const float* sp = sinT + row * 64 + 8 * kq;
    float c[8], s[8];
    *(float4*)(c)     = *(const float4*)(cp);
    *(float4*)(c + 4) = *(const float4*)(cp + 4);
    *(float4*)(s)     = *(const float4*)(sp);
    *(float4*)(s + 4) = *(const float4*)(sp + 4);
    BF8 o1, o2;
    #pragma unroll
    for (int j = 0; j < 8; ++j) {
      float x1 = b2f((ushort_t)x1v[j]);
      float x2 = b2f((ushort_t)x2v[j]);
      o1.s[j] = f2b(x1 * c[j] - x2 * s[j]);
      o2.s[j] = f2b(x1 * s[j] + x2 * c[j]);
    }
    bq[0] = *(const bf16x8*)&o1;
    bq[1] = *(const bf16x8*)&o2;
  }

  f32x4 Oa[4];
  #pragma unroll
  for (int mt = 0; mt < 4; ++mt) Oa[mt] = {0.f, 0.f, 0.f, 0.f};
  float m = -1e30f, l = 0.f;
  const float SCL = 0.125f * 1.44269504f;   // /sqrt(64) * log2(e)

  const int ntiles = (q0 + 15) / 64 + 1;
  for (int t = 0; t < ntiles; ++t) {
    const int base = t * 64;
    // ---- Sc^T = K.Q^T ----
    f32x4 sc[4];
    #pragma unroll
    for (int mt = 0; mt < 4; ++mt) sc[mt] = {0.f, 0.f, 0.f, 0.f};
    #pragma unroll
    for (int kc = 0; kc < 2; ++kc) {
      bf16x8 ak[4];
      #pragma unroll
      for (int mt = 0; mt < 4; ++mt)
        ak[mt] = *(const bf16x8*)&KBh[(size_t)(base + 16 * mt + lm) * HD + 8 * kq + 32 * kc];
      #pragma unroll
      for (int mt = 0; mt < 4; ++mt)
        sc[mt] = __builtin_amdgcn_mfma_f32_16x16x32_bf16(ak[mt], bq[kc], sc[mt], 0, 0, 0);
    }
    // ---- online softmax (log2 domain), per q = per lane column lm ----
    const bool diag = (t == ntiles - 1);   // non-diag tiles are provably unmasked
    const int qg = q0 + lm;
    #pragma unroll
    for (int mt = 0; mt < 4; ++mt)
      #pragma unroll
      for (int r = 0; r < 4; ++r) {
        float sv = sc[mt][r] * SCL;
        if (diag && (base + 16 * mt + 4 * kq + r > qg)) sv = -1e9f;
        sc[mt][r] = sv;
      }
    float mx = sc[0][0];
    #pragma unroll
    for (int mt = 0; mt < 4; ++mt)
      #pragma unroll
      for (int r = 0; r < 4; ++r) mx = fmaxf(mx, sc[mt][r]);
    mx = fmaxf(mx, __shfl_xor(mx, 16));
    mx = fmaxf(mx, __shfl_xor(mx, 32));
    const float mn = fmaxf(m, mx);
    const float al = exp2f(m - mn);
    m = mn;
    float sum = 0.f;
    #pragma unroll
    for (int mt = 0; mt < 4; ++mt)
      #pragma unroll
      for (int r = 0; r < 4; ++r) {
        float p = exp2f(sc[mt][r] - mn);
        sc[mt][r] = p;
        sum += p;
      }
    sum += __shfl_xor(sum, 16);
    sum += __shfl_xor(sum, 32);
    l = l * al + sum;
    #pragma unroll
    for (int mt = 0; mt < 4; ++mt)
      #pragma unroll
      for (int r = 0; r < 4; ++r) Oa[mt][r] *= al;
    ushort_t* pw = &Ps[wv][lm][4 * kq];
    #pragma unroll
    for (int mt = 0; mt < 4; ++mt) {
      *(uint_t*)(pw + 16 * mt)     = pack2(sc[mt][0], sc[mt][1]);
      *(uint_t*)(pw + 16 * mt + 2) = pack2(sc[mt][2], sc[mt][3]);
    }
    // ---- out^T += V^T . P^T ----
    #pragma unroll
    for (int kc = 0; kc < 2; ++kc) {
      bf16x8 av[4], pb;
      #pragma unroll
      for (int mt = 0; mt < 4; ++mt)
        av[mt] = *(const bf16x8*)&VTh[(size_t)(16 * mt + lm) * S_LEN + base + 8 * kq + 32 * kc];
      const ushort_t* prr = &Ps[wv][lm][8 * kq + 32 * kc];
      union { uint_t u[4]; bf16x8 v; } pu;
      pu.u[0] = *(const uint_t*)(prr);
      pu.u[1] = *(const uint_t*)(prr + 2);
      pu.u[2] = *(const uint_t*)(prr + 4);
      pu.u[3] = *(const uint_t*)(prr + 6);
      pb = pu.v;
      #pragma unroll
      for (int mt = 0; mt < 4; ++mt)
        Oa[mt] = __builtin_amdgcn_mfma_f32_16x16x32_bf16(av[mt], pb, Oa[mt], 0, 0, 0);
    }
  }
  // ---- epilogue ----
  const float inv = 1.f / l;
  ushort_t* orow = O + (size_t)(q0 + lm) * DMODEL + h * HD + 4 * kq;
  #pragma unroll
  for (int mt = 0; mt < 4; ++mt) {
    *(uint_t*)(orow + 16 * mt)     = pack2(Oa[mt][0] * inv, Oa[mt][1] * inv);
    *(uint_t*)(orow + 16 * mt + 2) = pack2(Oa[mt][2] * inv, Oa[mt][3] * inv);
  }
}

extern "C" void kernel_launch(void* const* d_in, const int* in_sizes, int n_in,
                              void* d_out, int out_size, void* d_ws, size_t ws_size,
                              hipStream_t stream) {
  const float* x    = (const float*)d_in[0];
  const float* cosT = (const float*)d_in[1];
  const float* sinT = (const float*)d_in[2];
  // d_in[3] = mask: causal -1e9, applied analytically (identical semantics)
  const float* wq   = (const float*)d_in[4];
  const float* wk   = (const float*)d_in[5];
  const float* wv   = (const float*)d_in[6];
  const float* wo   = (const float*)d_in[7];

  float* out   = (float*)d_out;                    // [S, 2048] fp32
  float* out_k = out + (size_t)S_LEN * DMODEL;     // new_k [S, 8, 64] fp32
  float* out_v = out_k + (size_t)S_LEN * DKV;      // new_v [S, 8, 64] fp32

  const size_t MB = 1024 * 1024;
  ushort_t* ws    = (ushort_t*)d_ws;               // ws_size >= 24 MB (confirmed r8)
  ushort_t* wqT   = ws;                            // [0,8M)  wqT bf16 [2048][2048]; later woT
  ushort_t* wkT   = ws + 4 * MB;                   // [8,10M) wkT; wvT follows -> BT [3072][2048]
  ushort_t* ws_q  = ws + 6 * MB;                   // [12,20M) q bf16 [S][2048]
  ushort_t* ws_kb = ws + 10 * MB;                  // [20,22M) KB bf16 [8][S][64]
  ushort_t* ws_vt = ws + 11 * MB;                  // [22,24M) VT bf16 [8][64][S]
  ushort_t* xb    = (ushort_t*)out;                // scratch in dead out region

  dim3 blk(256);
  // prework: bf16 conversions + weight transposes
  xb_kernel<<<(S_LEN * DMODEL / 8) / 256, 256, 0, stream>>>(x, xb);
  wT_kernel<<<dim3(32, 32), blk, 0, stream>>>(wq, wqT, DMODEL, DMODEL);
  wT_kernel<<<dim3(32, 8),  blk, 0, stream>>>(wk, wkT, DMODEL, DKV);
  wT_kernel<<<dim3(32, 8),  blk, 0, stream>>>(wv, wkT + (size_t)DKV * DMODEL, DMODEL, DKV);
  // fused q/k/v projection (N = 3072), 768 blocks = 3/CU
  gemm_proj<<<dim3(3072 / 64, S_LEN / 128), blk, 0, stream>>>(xb, wqT, ws_q, out_k, out_v);
  // wo^T overwrites wqT (dead after gemm_proj)
  wT_kernel<<<dim3(32, 32), blk, 0, stream>>>(wo, wqT, DMODEL, DMODEL);
  // rope(K) in-place + bf16 KB; V transpose
  rope_kb_kernel<<<(S_LEN * NKV * 32) / 256, 256, 0, stream>>>(out_k, ws_kb, cosT, sinT);
  vt_kernel<<<dim3(S_LEN / 64, NKV), blk, 0, stream>>>(out_v, ws_vt);
  // attention (16-q groups, paired, rope-on-Q fused), in-place on q
  attn_mfma3<<<NHQ * 64, 128, 0, stream>>>(ws_q, ws_kb, ws_vt, cosT, sinT, ws_q);
  // final projection, 512 blocks = 2/CU
  gemm_out<<<dim3(DMODEL / 64, S_LEN / 128), blk, 0, stream>>>(ws_q, wqT, out);
}

// Round 10
// 305.902 us; speedup vs baseline: 1.1311x; 1.1311x over previous
//
#include <hip/hip_runtime.h>

#define S_LEN 2048
#define NHQ 32
#define NKV 8
#define HD 64
#define DMODEL 2048   // NHQ*HD
#define DKV 512       // NKV*HD

typedef unsigned short ushort_t;
typedef unsigned int uint_t;

typedef __attribute__((ext_vector_type(8))) short bf16x8;
typedef __attribute__((ext_vector_type(4))) float f32x4;

__device__ __forceinline__ float b2f(ushort_t h) {
  union { uint_t u; float f; } v;
  v.u = ((uint_t)h) << 16;
  return v.f;
}
// round-to-nearest-even fp32 -> bf16
__device__ __forceinline__ ushort_t f2b(float f) {
  union { float f; uint_t u; } v;
  v.f = f;
  uint_t r = v.u + 0x7fffu + ((v.u >> 16) & 1u);
  return (ushort_t)(r >> 16);
}
__device__ __forceinline__ uint_t pack2(float lo, float hi) {
  return (uint_t)f2b(lo) | ((uint_t)f2b(hi) << 16);
}

union BF8 { uint4 v; ushort_t s[8]; };

// async 16B global -> LDS (wave-uniform LDS base + lane*16)
__device__ __forceinline__ void gl_lds16(const ushort_t* g, ushort_t* l) {
  __builtin_amdgcn_global_load_lds((const __attribute__((address_space(1))) void*)g,
                                   (__attribute__((address_space(3))) void*)l, 16, 0, 0);
}

// x fp32 -> bf16 flat (8 elems/thread)
__global__ void xb_kernel(const float* __restrict__ X, ushort_t* __restrict__ XB) {
  int i = (blockIdx.x * 256 + threadIdx.x) * 8;
  float4 a = *(const float4*)(X + i);
  float4 b = *(const float4*)(X + i + 4);
  BF8 u;
  u.s[0] = f2b(a.x); u.s[1] = f2b(a.y); u.s[2] = f2b(a.z); u.s[3] = f2b(a.w);
  u.s[4] = f2b(b.x); u.s[5] = f2b(b.y); u.s[6] = f2b(b.z); u.s[7] = f2b(b.w);
  *(uint4*)(XB + i) = u.v;
}

// W [K=2048][N] fp32 -> WT [N][K] bf16 (64x64 LDS tiles)
__global__ __launch_bounds__(256) void wT_kernel(const float* __restrict__ W,
                                                 ushort_t* __restrict__ WT,
                                                 int K, int N) {
  __shared__ ushort_t T[64][66];
  const int tid = threadIdx.x;
  const int r0 = blockIdx.x * 64;   // K dim
  const int c0 = blockIdx.y * 64;   // N dim
  {
    const int rl = tid >> 2, cp = (tid & 3) * 16;
    const float* p = W + (size_t)(r0 + rl) * N + c0 + cp;
    float v[16];
    *(float4*)(v)      = *(const float4*)(p);
    *(float4*)(v + 4)  = *(const float4*)(p + 4);
    *(float4*)(v + 8)  = *(const float4*)(p + 8);
    *(float4*)(v + 12) = *(const float4*)(p + 12);
    #pragma unroll
    for (int j = 0; j < 16; ++j) T[cp + j][rl] = f2b(v[j]);
  }
  __syncthreads();
  {
    const int cl = tid >> 2, rp = (tid & 3) * 16;
    uint_t u[8];
    #pragma unroll
    for (int i = 0; i < 8; ++i) u[i] = *(const uint_t*)&T[cl][rp + 2 * i];
    ushort_t* outp = WT + (size_t)(c0 + cl) * K + r0 + rp;
    *(uint4*)(outp)     = make_uint4(u[0], u[1], u[2], u[3]);
    *(uint4*)(outp + 8) = make_uint4(u[4], u[5], u[6], u[7]);
  }
}

// GEMM core, 128(M)x64(N) tile, BK=32, 4 waves each 64x32 (4x2 MFMA tiles).
// A bf16 [M][K], BT bf16 [N][K] row-major. Staging via global_load_lds w=16:
// As/Bs UNPADDED (lds dest = wave base + lane*16B); lane l of wave w stages
// row base + (l>>2), k-col (l&3)*8 — m97-verified layout.
__device__ __forceinline__ void gemm_core_gl(const ushort_t* __restrict__ A,
                                             const ushort_t* __restrict__ BT,
                                             int K, int tile_m, int tile_n,
                                             f32x4 (&acc)[4][2],
                                             ushort_t (*As)[32], ushort_t (*Bs)[32]) {
  const int tid = threadIdx.x;
  const int lane = tid & 63;
  const int w = tid >> 6;
  const int wr = (w >> 1) * 64, wc = (w & 1) * 32;
  const int lm = lane & 15, kq = lane >> 4;

  #pragma unroll
  for (int i = 0; i < 4; ++i)
    #pragma unroll
    for (int j = 0; j < 2; ++j) acc[i][j] = {0.f, 0.f, 0.f, 0.f};

  // per-lane global sources (k advances by kt)
  const ushort_t* ap0 = A  + (size_t)(tile_m + w * 32 + (lane >> 2)) * K + (lane & 3) * 8;
  const ushort_t* ap1 = ap0 + (size_t)16 * K;
  const ushort_t* bp  = BT + (size_t)(tile_n + w * 16 + (lane >> 2)) * K + (lane & 3) * 8;
  // wave-uniform LDS bases (ushort units)
  ushort_t* asb0 = &As[0][0] + w * 1024;        // rows w*32..w*32+15
  ushort_t* asb1 = asb0 + 512;                  // rows w*32+16..w*32+31
  ushort_t* bsb  = &Bs[0][0] + w * 512;         // rows w*16..w*16+15

  for (int kt = 0; kt < K; kt += 32) {
    __syncthreads();   // previous iter's frags consumed
    gl_lds16(ap0 + kt, asb0);
    gl_lds16(ap1 + kt, asb1);
    gl_lds16(bp  + kt, bsb);
    __syncthreads();   // drains vmcnt (async LDS writes complete)
    bf16x8 af[4], bfr[2];
    #pragma unroll
    for (int i = 0; i < 4; ++i) af[i]  = *(const bf16x8*)&As[wr + 16 * i + lm][kq * 8];
    #pragma unroll
    for (int j = 0; j < 2; ++j) bfr[j] = *(const bf16x8*)&Bs[wc + 16 * j + lm][kq * 8];
    #pragma unroll
    for (int i = 0; i < 4; ++i)
      #pragma unroll
      for (int j = 0; j < 2; ++j)
        acc[i][j] = __builtin_amdgcn_mfma_f32_16x16x32_bf16(af[i], bfr[j], acc[i][j], 0, 0, 0);
  }
}

// Fused q/k/v projection: BT = [wqT|wkT|wvT] (N=3072). Split epilogue.
__global__ __launch_bounds__(256) void gemm_proj(const ushort_t* __restrict__ A,
                                                 const ushort_t* __restrict__ BT,
                                                 ushort_t* __restrict__ Qo,
                                                 float* __restrict__ Ko,
                                                 float* __restrict__ Vo) {
  __shared__ ushort_t As[128][32];
  __shared__ ushort_t Bs[64][32];
  const int lane = threadIdx.x & 63;
  const int w = threadIdx.x >> 6;
  const int wr = (w >> 1) * 64, wc = (w & 1) * 32;
  const int lm = lane & 15, kq = lane >> 4;
  const int tile_m = blockIdx.y * 128, tile_n = blockIdx.x * 64;
  f32x4 acc[4][2];
  gemm_core_gl(A, BT, DMODEL, tile_m, tile_n, acc, As, Bs);
  #pragma unroll
  for (int i = 0; i < 4; ++i)
    #pragma unroll
    for (int j = 0; j < 2; ++j)
      #pragma unroll
      for (int r = 0; r < 4; ++r) {
        const int row = tile_m + wr + 16 * i + kq * 4 + r;
        const int col = tile_n + wc + 16 * j + lm;
        const float v = acc[i][j][r];
        if (col < 2048)      Qo[(size_t)row * DMODEL + col] = f2b(v);
        else if (col < 2560) Ko[(size_t)row * DKV + col - 2048] = v;
        else                 Vo[(size_t)row * DKV + col - 2560] = v;
      }
}

// Final projection: C fp32 [M][2048]
__global__ __launch_bounds__(256) void gemm_out(const ushort_t* __restrict__ A,
                                                const ushort_t* __restrict__ BT,
                                                float* __restrict__ C) {
  __shared__ ushort_t As[128][32];
  __shared__ ushort_t Bs[64][32];
  const int lane = threadIdx.x & 63;
  const int w = threadIdx.x >> 6;
  const int wr = (w >> 1) * 64, wc = (w & 1) * 32;
  const int lm = lane & 15, kq = lane >> 4;
  const int tile_m = blockIdx.y * 128, tile_n = blockIdx.x * 64;
  f32x4 acc[4][2];
  gemm_core_gl(A, BT, DMODEL, tile_m, tile_n, acc, As, Bs);
  #pragma unroll
  for (int i = 0; i < 4; ++i)
    #pragma unroll
    for (int j = 0; j < 2; ++j)
      #pragma unroll
      for (int r = 0; r < 4; ++r) {
        const int row = tile_m + wr + 16 * i + kq * 4 + r;
        const int col = tile_n + wc + 16 * j + lm;
        C[(size_t)row * DMODEL + col] = acc[i][j][r];
      }
}

// Fused rope(K) in-place fp32 + bf16 KB [hk][s][64] copy.
__global__ void rope_kb_kernel(float* Kio, ushort_t* __restrict__ KB,
                               const float* __restrict__ cosT, const float* __restrict__ sinT) {
  int idx = blockIdx.x * 256 + threadIdx.x;   // < S*8*32
  int d = idx & 31;
  int hk = (idx >> 5) & 7;
  int s = idx >> 8;
  float* p = Kio + (size_t)s * DKV + hk * HD + d;
  float x1 = p[0], x2 = p[32];
  float c = cosT[s * 64 + d], sn = sinT[s * 64 + d];
  float n1 = x1 * c - x2 * sn;
  float n2 = x1 * sn + x2 * c;
  p[0] = n1; p[32] = n2;
  ushort_t* kb = KB + (size_t)hk * S_LEN * HD + (size_t)s * HD + d;
  kb[0] = f2b(n1); kb[32] = f2b(n2);
}

// V: fp32 [s][512] -> bf16 transposed VT [hk][64][s]
__global__ __launch_bounds__(256) void vt_kernel(const float* __restrict__ V,
                                                 ushort_t* __restrict__ VT) {
  __shared__ ushort_t T[64][66];
  const int tid = threadIdx.x;
  const int s0 = blockIdx.x * 64;
  const int hk = blockIdx.y;
  {
    const int s_l = tid >> 2, dp = (tid & 3) * 16;
    const float* p = V + (size_t)(s0 + s_l) * DKV + hk * HD + dp;
    float v[16];
    *(float4*)(v)      = *(const float4*)(p);
    *(float4*)(v + 4)  = *(const float4*)(p + 4);
    *(float4*)(v + 8)  = *(const float4*)(p + 8);
    *(float4*)(v + 12) = *(const float4*)(p + 12);
    #pragma unroll
    for (int j = 0; j < 16; ++j) T[dp + j][s_l] = f2b(v[j]);
  }
  __syncthreads();
  {
    const int d_l = tid >> 2, sp = (tid & 3) * 16;
    uint_t u[8];
    #pragma unroll
    for (int i = 0; i < 8; ++i) u[i] = *(const uint_t*)&T[d_l][sp + 2 * i];
    ushort_t* outp = VT + (size_t)hk * HD * S_LEN + (size_t)d_l * S_LEN + s0 + sp;
    *(uint4*)(outp)     = make_uint4(u[0], u[1], u[2], u[3]);
    *(uint4*)(outp + 8) = make_uint4(u[4], u[5], u[6], u[7]);
  }
}

// MFMA flash attention v2 (verified round 8; only change: log2-domain exp,
// numerics validated in round 9). 128-thread block = 2 independent waves on
// paired 32-query groups (g, 63-g) -> uniform 33 key-tiles/block.
__global__ __launch_bounds__(128) void attn_mfma2(const ushort_t* Q,
                                                  const ushort_t* __restrict__ KB,
                                                  const ushort_t* __restrict__ VT,
                                                  const float* __restrict__ cosT,
                                                  const float* __restrict__ sinT,
                                                  ushort_t* O) {
  __shared__ ushort_t Ps[2][32][66];
  const int wv = threadIdx.x >> 6;
  const int lane = threadIdx.x & 63;
  const int lm = lane & 15, kq = lane >> 4;
  const int h = blockIdx.x >> 5;
  const int pr_ = blockIdx.x & 31;
  const int g = wv ? (63 - pr_) : pr_;
  const int q0 = g * 32;
  const int hk = h >> 2;
  const ushort_t* KBh = KB + (size_t)hk * S_LEN * HD;
  const ushort_t* VTh = VT + (size_t)hk * HD * S_LEN;
  const float SCL = 0.125f * 1.44269504f;   // /sqrt(64) * log2(e)

  // hoisted Q B-frags with in-register RoPE
  bf16x8 bq[2][2];
  #pragma unroll
  for (int nt = 0; nt < 2; ++nt) {
    const int row = q0 + 16 * nt + lm;
    const ushort_t* qp = Q + (size_t)row * DMODEL + h * HD + 8 * kq;
    bf16x8 x1v = *(const bf16x8*)qp;
    bf16x8 x2v = *(const bf16x8*)(qp + 32);
    const float* cp = cosT + row * 64 + 8 * kq;
    const float* sp = sinT + row * 64 + 8 * kq;
    float c[8], s[8];
    *(float4*)(c)     = *(const float4*)(cp);
    *(float4*)(c + 4) = *(const float4*)(cp + 4);
    *(float4*)(s)     = *(const float4*)(sp);
    *(float4*)(s + 4) = *(const float4*)(sp + 4);
    BF8 o1, o2;
    #pragma unroll
    for (int j = 0; j < 8; ++j) {
      float x1 = b2f((ushort_t)x1v[j]);
      float x2 = b2f((ushort_t)x2v[j]);
      o1.s[j] = f2b(x1 * c[j] - x2 * s[j]);
      o2.s[j] = f2b(x1 * s[j] + x2 * c[j]);
    }
    bq[nt][0] = *(const bf16x8*)&o1;
    bq[nt][1] = *(const bf16x8*)&o2;
  }

  f32x4 Oa[4][2];
  #pragma unroll
  for (int mt = 0; mt < 4; ++mt) { Oa[mt][0] = {0.f,0.f,0.f,0.f}; Oa[mt][1] = {0.f,0.f,0.f,0.f}; }
  float m[2] = {-1e30f, -1e30f}, l[2] = {0.f, 0.f};

  const int ntiles = (q0 + 31) / 64 + 1;
  for (int t = 0; t < ntiles; ++t) {
    const int base = t * 64;
    f32x4 sc[4][2];
    #pragma unroll
    for (int mt = 0; mt < 4; ++mt) { sc[mt][0] = {0.f,0.f,0.f,0.f}; sc[mt][1] = {0.f,0.f,0.f,0.f}; }
    #pragma unroll
    for (int kc = 0; kc < 2; ++kc) {
      bf16x8 ak[4];
      #pragma unroll
      for (int mt = 0; mt < 4; ++mt)
        ak[mt] = *(const bf16x8*)&KBh[(size_t)(base + 16 * mt + lm) * HD + 8 * kq + 32 * kc];
      #pragma unroll
      for (int mt = 0; mt < 4; ++mt)
        #pragma unroll
        for (int nt = 0; nt < 2; ++nt)
          sc[mt][nt] = __builtin_amdgcn_mfma_f32_16x16x32_bf16(ak[mt], bq[nt][kc], sc[mt][nt], 0, 0, 0);
    }
    const bool diag = (t == ntiles - 1);
    #pragma unroll
    for (int nt = 0; nt < 2; ++nt) {
      const int qg = q0 + 16 * nt + lm;
      #pragma unroll
      for (int mt = 0; mt < 4; ++mt)
        #pragma unroll
        for (int r = 0; r < 4; ++r) {
          float sv = sc[mt][nt][r] * SCL;
          if (diag && (base + 16 * mt + 4 * kq + r > qg)) sv = -1e9f;
          sc[mt][nt][r] = sv;
        }
      float mx = sc[0][nt][0];
      #pragma unroll
      for (int mt = 0; mt < 4; ++mt)
        #pragma unroll
        for (int r = 0; r < 4; ++r) mx = fmaxf(mx, sc[mt][nt][r]);
      mx = fmaxf(mx, __shfl_xor(mx, 16));
      mx = fmaxf(mx, __shfl_xor(mx, 32));
      const float mn = fmaxf(m[nt], mx);
      const float al = exp2f(m[nt] - mn);
      m[nt] = mn;
      float sum = 0.f;
      #pragma unroll
      for (int mt = 0; mt < 4; ++mt)
        #pragma unroll
        for (int r = 0; r < 4; ++r) {
          float p = exp2f(sc[mt][nt][r] - mn);
          sc[mt][nt][r] = p;
          sum += p;
        }
      sum += __shfl_xor(sum, 16);
      sum += __shfl_xor(sum, 32);
      l[nt] = l[nt] * al + sum;
      #pragma unroll
      for (int mt = 0; mt < 4; ++mt)
        #pragma unroll
        for (int r = 0; r < 4; ++r) Oa[mt][nt][r] *= al;
      ushort_t* pw = &Ps[wv][16 * nt + lm][4 * kq];
      #pragma unroll
      for (int mt = 0; mt < 4; ++mt) {
        *(uint_t*)(pw + 16 * mt)     = pack2(sc[mt][nt][0], sc[mt][nt][1]);
        *(uint_t*)(pw + 16 * mt + 2) = pack2(sc[mt][nt][2], sc[mt][nt][3]);
      }
    }
    #pragma unroll
    for (int kc = 0; kc < 2; ++kc) {
      bf16x8 av[4], pb[2];
      #pragma unroll
      for (int mt = 0; mt < 4; ++mt)
        av[mt] = *(const bf16x8*)&VTh[(size_t)(16 * mt + lm) * S_LEN + base + 8 * kq + 32 * kc];
      #pragma unroll
      for (int nt = 0; nt < 2; ++nt) {
        const ushort_t* prr = &Ps[wv][16 * nt + lm][8 * kq + 32 * kc];
        union { uint_t u[4]; bf16x8 v; } pu;
        pu.u[0] = *(const uint_t*)(prr);
        pu.u[1] = *(const uint_t*)(prr + 2);
        pu.u[2] = *(const uint_t*)(prr + 4);
        pu.u[3] = *(const uint_t*)(prr + 6);
        pb[nt] = pu.v;
      }
      #pragma unroll
      for (int mt = 0; mt < 4; ++mt)
        #pragma unroll
        for (int nt = 0; nt < 2; ++nt)
          Oa[mt][nt] = __builtin_amdgcn_mfma_f32_16x16x32_bf16(av[mt], pb[nt], Oa[mt][nt], 0, 0, 0);
    }
  }
  #pragma unroll
  for (int nt = 0; nt < 2; ++nt) {
    const float inv = 1.f / l[nt];
    ushort_t* orow = O + (size_t)(q0 + 16 * nt + lm) * DMODEL + h * HD + 4 * kq;
    #pragma unroll
    for (int mt = 0; mt < 4; ++mt) {
      *(uint_t*)(orow + 16 * mt)     = pack2(Oa[mt][nt][0] * inv, Oa[mt][nt][1] * inv);
      *(uint_t*)(orow + 16 * mt + 2) = pack2(Oa[mt][nt][2] * inv, Oa[mt][nt][3] * inv);
    }
  }
}

extern "C" void kernel_launch(void* const* d_in, const int* in_sizes, int n_in,
                              void* d_out, int out_size, void* d_ws, size_t ws_size,
                              hipStream_t stream) {
  const float* x    = (const float*)d_in[0];
  const float* cosT = (const float*)d_in[1];
  const float* sinT = (const float*)d_in[2];
  // d_in[3] = mask: causal -1e9, applied analytically (identical semantics)
  const float* wq   = (const float*)d_in[4];
  const float* wk   = (const float*)d_in[5];
  const float* wv   = (const float*)d_in[6];
  const float* wo   = (const float*)d_in[7];

  float* out   = (float*)d_out;                    // [S, 2048] fp32
  float* out_k = out + (size_t)S_LEN * DMODEL;     // new_k [S, 8, 64] fp32
  float* out_v = out_k + (size_t)S_LEN * DKV;      // new_v [S, 8, 64] fp32

  const size_t MB = 1024 * 1024;
  ushort_t* ws    = (ushort_t*)d_ws;               // ws_size >= 24 MB (confirmed r8)
  ushort_t* wqT   = ws;                            // [0,8M)  wqT bf16 [2048][2048]; later woT
  ushort_t* wkT   = ws + 4 * MB;                   // [8,10M) wkT; wvT follows -> BT [3072][2048]
  ushort_t* ws_q  = ws + 6 * MB;                   // [12,20M) q bf16 [S][2048]
  ushort_t* ws_kb = ws + 10 * MB;                  // [20,22M) KB bf16 [8][S][64]
  ushort_t* ws_vt = ws + 11 * MB;                  // [22,24M) VT bf16 [8][64][S]
  ushort_t* xb    = (ushort_t*)out;                // scratch in dead out region

  dim3 blk(256);
  // prework: bf16 conversions + weight transposes
  xb_kernel<<<(S_LEN * DMODEL / 8) / 256, 256, 0, stream>>>(x, xb);
  wT_kernel<<<dim3(32, 32), blk, 0, stream>>>(wq, wqT, DMODEL, DMODEL);
  wT_kernel<<<dim3(32, 8),  blk, 0, stream>>>(wk, wkT, DMODEL, DKV);
  wT_kernel<<<dim3(32, 8),  blk, 0, stream>>>(wv, wkT + (size_t)DKV * DMODEL, DMODEL, DKV);
  // fused q/k/v projection (N = 3072), 768 blocks, global_load_lds staging
  gemm_proj<<<dim3(3072 / 64, S_LEN / 128), blk, 0, stream>>>(xb, wqT, ws_q, out_k, out_v);
  // wo^T overwrites wqT (dead after gemm_proj)
  wT_kernel<<<dim3(32, 32), blk, 0, stream>>>(wo, wqT, DMODEL, DMODEL);
  // rope(K) in-place + bf16 KB; V transpose
  rope_kb_kernel<<<(S_LEN * NKV * 32) / 256, 256, 0, stream>>>(out_k, ws_kb, cosT, sinT);
  vt_kernel<<<dim3(S_LEN / 64, NKV), blk, 0, stream>>>(out_v, ws_vt);
  // attention (verified 32-q pairing, rope-on-Q fused), in-place on q
  attn_mfma2<<<NHQ * 32, 128, 0, stream>>>(ws_q, ws_kb, ws_vt, cosT, sinT, ws_q);
  // final projection, 512 blocks
  gemm_out<<<dim3(DMODEL / 64, S_LEN / 128), blk, 0, stream>>>(ws_q, wqT, out);
}